// Round 3
// baseline (2595.794 us; speedup 1.0000x reference)
//
#include <hip/hip_runtime.h>

// Causal bag-of-words: out[b,t,c] = mean(x[b,0..t,c]).
// SINGLE-PASS decoupled-lookback scan along T (Merrill-Garland style),
// dispatch-order-safe via atomic ticket. x is read exactly once.
//
// Shapes: B=8, T=8192, C=512 (row-major B,T,C). All float32.
// Block = 256 threads = (c4 in [0,128)) x (half in {0,1}); each thread owns
// 8 rows x 1 float4 of its chunk (L=16 rows), register-resident end-to-end.
//
// ws layout:
//   meta  : uint[16 + NBLK]   meta[0] = ticket counter, flags at meta+16
//   agg   : float4[NBLK][C4]  chunk aggregates   (offset 64 KiB)
//   pref  : float4[NBLK][C4]  inclusive prefixes (follows agg)
// Prologue kernel zeroes meta each launch (harness poisons ws).

constexpr int B    = 8;
constexpr int T    = 8192;
constexpr int C    = 512;
constexpr int C4   = C / 4;      // 128 float4 per row
constexpr int L    = 16;         // rows per chunk
constexpr int NCH  = T / L;      // 512 chunks per b
constexpr int NBLK = B * NCH;    // 4096 blocks
constexpr int RPT  = L / 2;      // 8 rows per thread

typedef float f32x4 __attribute__((ext_vector_type(4)));

__device__ __forceinline__ float4 f4add(float4 a, float4 b) {
    return make_float4(a.x + b.x, a.y + b.y, a.z + b.z, a.w + b.w);
}

__global__ __launch_bounds__(256) void cbow_init(uint* __restrict__ meta) {
    const int i = blockIdx.x * 256 + threadIdx.x;
    if (i < 16 + NBLK) meta[i] = 0u;
}

__global__ __launch_bounds__(256) void cbow_lookback(
        const float4* __restrict__ x, float4* __restrict__ out,
        uint* __restrict__ meta,
        float4* __restrict__ agg, float4* __restrict__ pref) {
    const int c4   = threadIdx.x & (C4 - 1);
    const int half = threadIdx.x >> 7;       // 0: waves 0-1, 1: waves 2-3

    __shared__ uint   s_ticket;
    __shared__ float4 s_part[2][C4];
    __shared__ float4 s_acc[C4];

    // Ticket: chunks of a given b are issued in increasing order, and a
    // ticket is only ever held by a RUNNING block -> lookback cannot
    // deadlock regardless of dispatch order / co-residency.
    if (threadIdx.x == 0) s_ticket = atomicAdd(meta, 1u);
    __syncthreads();
    const uint t     = s_ticket;
    const int  b     = (int)(t & (B - 1));
    const int  chunk = (int)(t >> 3);
    const int  g     = b * NCH + chunk;
    uint* flags = meta + 16;

    // Load this thread's 8 rows of the chunk (register-resident).
    const int r0 = chunk * L + half * RPT;
    const float4* p = x + ((size_t)(b * T + r0)) * C4 + c4;
    float4 v[RPT];
#pragma unroll
    for (int k = 0; k < RPT; ++k) v[k] = p[k * C4];

    float4 ps = v[0];
#pragma unroll
    for (int k = 1; k < RPT; ++k) ps = f4add(ps, v[k]);
    s_part[half][c4] = ps;
    __syncthreads();
    const float4 part0 = s_part[0][c4];
    const float4 csum  = f4add(part0, s_part[1][c4]);

    // Publish chunk AGGREGATE (flag 0 -> 1).
    if (half == 1) agg[(size_t)g * C4 + c4] = csum;
    __threadfence();
    __syncthreads();
    if (threadIdx.x == 0)
        __hip_atomic_store(&flags[g], 1u, __ATOMIC_RELEASE,
                           __HIP_MEMORY_SCOPE_AGENT);

    // Lookback over predecessors (half0 threads, one per c4; flag address is
    // uniform across lanes so control flow is wave-uniform).
    if (half == 0) {
        float4 acc = make_float4(0.f, 0.f, 0.f, 0.f);
        int j = chunk - 1;
        while (j >= 0) {
            uint f = __hip_atomic_load(&flags[b * NCH + j], __ATOMIC_ACQUIRE,
                                       __HIP_MEMORY_SCOPE_AGENT);
            while (f == 0u) {
                __builtin_amdgcn_s_sleep(2);
                f = __hip_atomic_load(&flags[b * NCH + j], __ATOMIC_ACQUIRE,
                                      __HIP_MEMORY_SCOPE_AGENT);
            }
            if (f == 2u) {   // inclusive PREFIX available: short-circuit
                acc = f4add(acc, pref[(size_t)(b * NCH + j) * C4 + c4]);
                break;
            }
            acc = f4add(acc, agg[(size_t)(b * NCH + j) * C4 + c4]);
            --j;
        }
        s_acc[c4] = acc;
        pref[(size_t)g * C4 + c4] = f4add(acc, csum);
    }
    __threadfence();
    __syncthreads();
    // Publish inclusive PREFIX (flag 1 -> 2) ASAP: it's on other blocks'
    // critical path. Output stores happen after.
    if (threadIdx.x == 0)
        __hip_atomic_store(&flags[g], 2u, __ATOMIC_RELEASE,
                           __HIP_MEMORY_SCOPE_AGENT);

    // Exclusive prefix for this thread's first row.
    float4 run = s_acc[c4];
    if (half) run = f4add(run, part0);

    float4* o = out + ((size_t)(b * T + r0)) * C4 + c4;
#pragma unroll
    for (int k = 0; k < RPT; ++k) {
        run = f4add(run, v[k]);
        const float inv = __builtin_amdgcn_rcpf((float)(r0 + k + 1));
        f32x4 val = {run.x * inv, run.y * inv, run.z * inv, run.w * inv};
        __builtin_nontemporal_store(val, (f32x4*)(o + k * C4));
    }
}

extern "C" void kernel_launch(void* const* d_in, const int* in_sizes, int n_in,
                              void* d_out, int out_size, void* d_ws, size_t ws_size,
                              hipStream_t stream) {
    const float4* x   = (const float4*)d_in[0];
    float4*       out = (float4*)d_out;

    uint*   meta = (uint*)d_ws;
    float4* agg  = (float4*)((char*)d_ws + (64 << 10));
    float4* pref = agg + (size_t)NBLK * C4;   // total ws use ~16.1 MiB

    const int init_blocks = (16 + NBLK + 255) / 256;  // 17
    cbow_init<<<init_blocks, 256, 0, stream>>>(meta);
    cbow_lookback<<<NBLK, 256, 0, stream>>>(x, out, meta, agg, pref);
}

// Round 5
// 273.475 us; speedup vs baseline: 9.4919x; 9.4919x over previous
//
#include <hip/hip_runtime.h>

// Causal bag-of-words: out[b,t,c] = mean(x[b,0..t,c]).
// SINGLE kernel, no inter-block communication, x read once (+0.5 redundant
// L3-warm read of segment 0): each block owns a 64B-wide channel strip
// (G=4 float4) of one (b, T-segment) and performs the full sequential scan
// locally: per-thread serial sum of 4 consecutive rows -> 16-wide __shfl_up
// wave scan -> 4-entry LDS inter-wave combine -> carry in registers.
// Segment-1 blocks first stream-sum segment 0 (concurrently being read by
// segment-0 blocks -> L2/L3 hits) to obtain their initial carry.
//
// Shapes: B=8, T=8192, C=512 (row-major B,T,C). All float32.

constexpr int B       = 8;
constexpr int T       = 8192;
constexpr int C       = 512;
constexpr int C4      = C / 4;         // 128 float4 per row
constexpr int G       = 4;             // float4 columns per strip (64 B)
constexpr int NSTRIP  = C4 / G;        // 32 strips
constexpr int SEG     = 2;             // T-segments per column
constexpr int TSEG    = T / SEG;       // 4096 rows
constexpr int RPT     = 4;             // consecutive rows per thread per step
constexpr int RTHREAD = 64;            // r-threads per block (256 = RTHREAD*G)
constexpr int ROWS_STEP = RTHREAD * RPT;   // 256 rows per step
constexpr int NSTEP     = TSEG / ROWS_STEP; // 16 steps

typedef float f32x4 __attribute__((ext_vector_type(4)));

__device__ __forceinline__ float4 f4add(float4 a, float4 b) {
    return make_float4(a.x + b.x, a.y + b.y, a.z + b.z, a.w + b.w);
}
__device__ __forceinline__ float4 f4sub(float4 a, float4 b) {
    return make_float4(a.x - b.x, a.y - b.y, a.z - b.z, a.w - b.w);
}
__device__ __forceinline__ float4 shflup4(float4 v, int delta) {
    return make_float4(__shfl_up(v.x, delta), __shfl_up(v.y, delta),
                       __shfl_up(v.z, delta), __shfl_up(v.w, delta));
}
__device__ __forceinline__ float4 shfldn4(float4 v, int delta) {
    return make_float4(__shfl_down(v.x, delta), __shfl_down(v.y, delta),
                       __shfl_down(v.z, delta), __shfl_down(v.w, delta));
}

__global__ __launch_bounds__(256) void cbow_strip(
        const float4* __restrict__ x, float4* __restrict__ out) {
    const int bid   = blockIdx.x;            // [0, 512)
    const int seg   = bid & 1;
    const int strip = (bid >> 1) & (NSTRIP - 1);
    const int b     = bid >> 6;              // 2*32 = 64 blocks per b

    const int tx   = threadIdx.x;            // [0, 256)
    const int c    = tx & (G - 1);           // column within strip
    const int r    = tx >> 2;                // row-thread [0, 64)
    const int wave = tx >> 6;                // [0, 4)
    const int rl   = (tx & 63) >> 2;         // row-thread within wave [0, 16)

    const size_t colbase = (size_t)(b * T) * C4 + strip * G + c;

    __shared__ float4 sm[2][4][G];   // [parity][wave][c] step wave-totals
    __shared__ float4 smr[4][G];     // pre-pass reduction

    float4 carry = make_float4(0.f, 0.f, 0.f, 0.f);

    if (seg == 1) {
        // Pre-pass: carry = sum over segment 0 of this column.
        float4 acc = make_float4(0.f, 0.f, 0.f, 0.f);
        const float4* p = x + colbase;
        for (int i = 0; i < NSTEP; ++i) {
            const int t0 = i * ROWS_STEP + r * RPT;
            float4 a0 = p[(size_t)(t0 + 0) * C4];
            float4 a1 = p[(size_t)(t0 + 1) * C4];
            float4 a2 = p[(size_t)(t0 + 2) * C4];
            float4 a3 = p[(size_t)(t0 + 3) * C4];
            acc = f4add(acc, f4add(f4add(a0, a1), f4add(a2, a3)));
        }
        // Reduce over r: within wave (lane stride 4), then across waves.
        acc = f4add(acc, shfldn4(acc, 4));
        acc = f4add(acc, shfldn4(acc, 8));
        acc = f4add(acc, shfldn4(acc, 16));
        acc = f4add(acc, shfldn4(acc, 32));
        if (rl == 0) smr[wave][c] = acc;     // valid at rl==0 lanes
        __syncthreads();
        carry = f4add(f4add(smr[0][c], smr[1][c]),
                      f4add(smr[2][c], smr[3][c]));
    }

    const int tbase = seg * TSEG;
    const float4* p = x + colbase + (size_t)tbase * C4;
    float4*       o = out + colbase + (size_t)tbase * C4;

    // Prefetch step 0.
    float4 v[RPT];
#pragma unroll
    for (int k = 0; k < RPT; ++k)
        v[k] = p[(size_t)(r * RPT + k) * C4];

    for (int i = 0; i < NSTEP; ++i) {
        float4 cur0 = v[0], cur1 = v[1], cur2 = v[2], cur3 = v[3];
        if (i + 1 < NSTEP) {
            const int t0 = (i + 1) * ROWS_STEP + r * RPT;
#pragma unroll
            for (int k = 0; k < RPT; ++k)
                v[k] = p[(size_t)(t0 + k) * C4];
        }

        // Thread-local inclusive prefixes over 4 consecutive rows.
        const float4 p0 = cur0;
        const float4 p1 = f4add(p0, cur1);
        const float4 p2 = f4add(p1, cur2);
        const float4 p3 = f4add(p2, cur3);
        const float4 s  = p3;

        // Inclusive wave scan over rl (16 row-threads, lane stride 4).
        float4 sc = s;
        {
            float4 u;
            u = shflup4(sc, 4);  if (rl >= 1) sc = f4add(sc, u);
            u = shflup4(sc, 8);  if (rl >= 2) sc = f4add(sc, u);
            u = shflup4(sc, 16); if (rl >= 4) sc = f4add(sc, u);
            u = shflup4(sc, 32); if (rl >= 8) sc = f4add(sc, u);
        }
        if (rl == 15) sm[i & 1][wave][c] = sc;  // wave total
        __syncthreads();

        float4 off = carry;
        float4 stp = make_float4(0.f, 0.f, 0.f, 0.f);
#pragma unroll
        for (int w = 0; w < 4; ++w) {
            const float4 wt = sm[i & 1][w][c];
            stp = f4add(stp, wt);
            if (w < wave) off = f4add(off, wt);
        }
        const float4 excl = f4add(off, f4sub(sc, s));  // exclusive for row r*4

        const int trow = tbase + i * ROWS_STEP + r * RPT;
        float4 run = excl;
        const float4 pk[RPT] = {p0, p1, p2, p3};
#pragma unroll
        for (int k = 0; k < RPT; ++k) {
            run = f4add(excl, pk[k]);
            const float inv = __builtin_amdgcn_rcpf((float)(trow + k + 1));
            f32x4 val = {run.x * inv, run.y * inv, run.z * inv, run.w * inv};
            __builtin_nontemporal_store(
                val, (f32x4*)(o + (size_t)(i * ROWS_STEP + r * RPT + k) * C4));
        }
        carry = f4add(carry, stp);
    }
}

extern "C" void kernel_launch(void* const* d_in, const int* in_sizes, int n_in,
                              void* d_out, int out_size, void* d_ws, size_t ws_size,
                              hipStream_t stream) {
    const float4* x   = (const float4*)d_in[0];
    float4*       out = (float4*)d_out;

    const int grid = B * NSTRIP * SEG;   // 512 blocks
    cbow_strip<<<grid, 256, 0, stream>>>(x, out);
}

// Round 6
// 266.332 us; speedup vs baseline: 9.7464x; 1.0268x over previous
//
#include <hip/hip_runtime.h>

// Causal bag-of-words: out[b,t,c] = mean(x[b,0..t,c]).
// Two-pass chunked scan, tuned for HBM streaming efficiency:
//  - one 256-thread block per (b,chunk): each block's footprint is one
//    CONTIGUOUS 64 KiB region of x (L=32 rows x 2 KiB), read linearly
//    (wave-instrs walk sequential 1 KiB segments; block walks 4 KiB/step).
//  - 2048 blocks = 8 blocks/CU = 32 waves/CU (fills achieve 6.7 TB/s at
//    this occupancy; prior kernels had 8-16 waves/CU and ~2.5-3 TB/s).
//  - K2 fuses the chunk-prefix (parity-split halves, 4-deep batched,
//    ws is L2/L3-resident) with the streaming scan; per-thread 8
//    consecutive rows of one column, LDS carry hand-off per 16-row step;
//    nontemporal stores keep x resident in L3 for the re-read.
//
// Shapes: B=8, T=8192, C=512 (row-major B,T,C). All float32.

constexpr int B    = 8;
constexpr int T    = 8192;
constexpr int C    = 512;
constexpr int C4   = C / 4;      // 128 float4 per row
constexpr int L    = 32;         // rows per chunk
constexpr int NCH  = T / L;      // 256 chunks per b
constexpr int NBLK = B * NCH;    // 2048 blocks

typedef float f32x4 __attribute__((ext_vector_type(4)));

__device__ __forceinline__ float4 f4add(float4 a, float4 b) {
    return make_float4(a.x + b.x, a.y + b.y, a.z + b.z, a.w + b.w);
}

// ---- K1: per-(b,chunk) column sums; block reads its 64 KiB linearly ----
__global__ __launch_bounds__(256) void cbow_sums(
        const float4* __restrict__ x, float4* __restrict__ ws) {
    const int g     = blockIdx.x;
    const int b     = g >> 8;          // NCH = 256
    const int chunk = g & (NCH - 1);
    const int t     = threadIdx.x;

    const size_t base = ((size_t)(b * T) + (size_t)chunk * L) * C4;
    const float4* p = x + base + t;

    // 16 linear sweeps of 256 float4; element (k*256+t) has column t&127
    // (256 = 2*C4), row 2k + (t>>7)  ->  per-thread partial for one column.
    float4 acc = make_float4(0.f, 0.f, 0.f, 0.f);
    float4 buf[8];
#pragma unroll
    for (int h = 0; h < 2; ++h) {
#pragma unroll
        for (int k = 0; k < 8; ++k) buf[k] = p[(h * 8 + k) * 256];
#pragma unroll
        for (int k = 0; k < 8; ++k) acc = f4add(acc, buf[k]);
    }

    __shared__ float4 part[2][C4];
    part[t >> 7][t & (C4 - 1)] = acc;
    __syncthreads();
    if (t < C4) {
        ws[(size_t)(b * NCH + chunk) * C4 + t] = f4add(part[0][t], part[1][t]);
    }
}

// ---- K2: fused chunk-prefix + streaming scan + NT store ----------------
__global__ __launch_bounds__(256) void cbow_scan(
        const float4* __restrict__ x, const float4* __restrict__ ws,
        float4* __restrict__ out) {
    const int g     = blockIdx.x;
    const int b     = g >> 8;
    const int chunk = g & (NCH - 1);
    const int t     = threadIdx.x;
    const int c4    = t & (C4 - 1);
    const int rg    = t >> 7;          // half-block id (rows 0-7 / 8-15 of step)

    __shared__ float4 lp[2][C4];       // parity-split prefix partials
    __shared__ float4 ls[2][2][C4];    // [megastep][rg] 8-row sums

    // Exclusive prefix over preceding chunk sums; halves take alternate j.
    const float4* w = ws + (size_t)b * NCH * C4 + c4;
    float4 a0 = make_float4(0.f, 0.f, 0.f, 0.f);
    float4 a1 = a0, a2 = a0, a3 = a0;
    int j = rg;
    for (; j + 6 < chunk; j += 8) {
        a0 = f4add(a0, w[(size_t)(j + 0) * C4]);
        a1 = f4add(a1, w[(size_t)(j + 2) * C4]);
        a2 = f4add(a2, w[(size_t)(j + 4) * C4]);
        a3 = f4add(a3, w[(size_t)(j + 6) * C4]);
    }
    for (; j < chunk; j += 2) a0 = f4add(a0, w[(size_t)j * C4]);
    lp[rg][c4] = f4add(f4add(a0, a1), f4add(a2, a3));
    __syncthreads();
    float4 carry = f4add(lp[0][c4], lp[1][c4]);

    const size_t base = ((size_t)(b * T) + (size_t)chunk * L) * C4;
    const float4* p = x + base;
    float4*       o = out + base;

    float4 buf[8];
#pragma unroll
    for (int m = 0; m < 2; ++m) {
        const int r0 = m * 16 + rg * 8;      // first row this thread handles
#pragma unroll
        for (int k = 0; k < 8; ++k) buf[k] = p[(size_t)(r0 + k) * C4 + c4];

        float4 s8 = buf[0];
#pragma unroll
        for (int k = 1; k < 8; ++k) s8 = f4add(s8, buf[k]);
        ls[m][rg][c4] = s8;
        __syncthreads();

        float4 run = carry;
        if (rg) run = f4add(run, ls[m][0][c4]);

        const int trow = chunk * L + r0;
#pragma unroll
        for (int k = 0; k < 8; ++k) {
            run = f4add(run, buf[k]);
            const float inv = __builtin_amdgcn_rcpf((float)(trow + k + 1));
            f32x4 val = {run.x * inv, run.y * inv, run.z * inv, run.w * inv};
            __builtin_nontemporal_store(val, (f32x4*)(o + (size_t)(r0 + k) * C4 + c4));
        }
        carry = f4add(carry, f4add(ls[m][0][c4], ls[m][1][c4]));
    }
}

extern "C" void kernel_launch(void* const* d_in, const int* in_sizes, int n_in,
                              void* d_out, int out_size, void* d_ws, size_t ws_size,
                              hipStream_t stream) {
    const float4* x   = (const float4*)d_in[0];
    float4*       out = (float4*)d_out;
    float4*       ws  = (float4*)d_ws;   // needs B*NCH*C4*16 = 4 MiB

    cbow_sums<<<NBLK, 256, 0, stream>>>(x, ws);
    cbow_scan<<<NBLK, 256, 0, stream>>>(x, ws, out);
}